// Round 5
// baseline (136.380 us; speedup 1.0000x reference)
//
#include <hip/hip_runtime.h>

#define HH 512
#define WW 512
#define BB 64
#define HW (HH*WW)
#define CSTRIDE 40     // padded per-batch coeff stride (floats)
#define BGRP 16        // batches per block (4 y-groups)

typedef float v2f __attribute__((ext_vector_type(2)));
typedef float v4f __attribute__((ext_vector_type(4)));

// ---------------------------------------------------------------------------
// Compile-time construction + inversion of the 19x19 TPS system matrix.
// RBF rows pre-scaled by ln(2) so the kernel can use hw v_log_f32 (log2).
// ---------------------------------------------------------------------------
constexpr double cx_ln(double x) {
  int e = 0;
  while (x >= 2.0) { x *= 0.5; ++e; }
  while (x < 1.0)  { x *= 2.0; --e; }
  double z = (x - 1.0) / (x + 1.0);
  double z2 = z * z, term = z, sum = 0.0;
  for (int n = 1; n < 60; n += 2) { sum += term / n; term *= z2; }
  return 2.0 * sum + e * 0.69314718055994530942;
}

struct WMat { float w[19][16]; };

constexpr WMat build_wm() {
  const double Xc[4] = {-1.0, -1.0/3.0, 1.0/3.0, 1.0};
  double A[19][38] = {};
  for (int r = 0; r < 19; ++r) {
    for (int c = 0; c < 38; ++c) {
      double v = 0.0;
      if (c >= 19) {
        v = ((c - 19) == r) ? 1.0 : 0.0;
      } else if (r < 16 && c < 16) {
        double dx = Xc[r >> 2] - Xc[c >> 2];
        double dy = Xc[r & 3] - Xc[c & 3];
        double r2 = dx * dx + dy * dy;
        v = (r2 == 0.0) ? 0.0 : r2 * cx_ln(r2 + 1e-6);
      } else if (r < 16) {
        v = (c == 16) ? 1.0 : ((c == 17) ? Xc[r >> 2] : Xc[r & 3]);
      } else if (c < 16) {
        v = (r == 16) ? 1.0 : ((r == 17) ? Xc[c >> 2] : Xc[c & 3]);
      }
      A[r][c] = v;
    }
  }
  for (int k = 0; k < 19; ++k) {
    int best = k;
    double bv = A[k][k] < 0 ? -A[k][k] : A[k][k];
    for (int r = k + 1; r < 19; ++r) {
      double av = A[r][k] < 0 ? -A[r][k] : A[r][k];
      if (av > bv) { bv = av; best = r; }
    }
    if (best != k)
      for (int c = 0; c < 38; ++c) { double t = A[k][c]; A[k][c] = A[best][c]; A[best][c] = t; }
    double rp = 1.0 / A[k][k];
    for (int c = 0; c < 38; ++c) A[k][c] *= rp;
    for (int r = 0; r < 19; ++r) {
      if (r == k) continue;
      double f = A[r][k];
      for (int c = 0; c < 38; ++c) A[r][c] -= f * A[k][c];
    }
  }
  WMat wm = {};
  for (int i = 0; i < 19; ++i)
    for (int j = 0; j < 16; ++j)
      wm.w[i][j] = (float)(A[i][19 + j] * (i < 16 ? 0.69314718055994530942 : 1.0));
  return wm;
}

__device__ __constant__ WMat WM = build_wm();

__device__ __forceinline__ float fast_log2(float x) {
#if __has_builtin(__builtin_amdgcn_logf)
  return __builtin_amdgcn_logf(x);
#else
  return __log2f(x);
#endif
}

// ---------------------------------------------------------------------------
// Kernel 1: per-batch coefficients -> d_ws (tiny; lanes<38 each do a
// 16-length dot against the baked inverse).
// ---------------------------------------------------------------------------
__global__ __launch_bounds__(64) void tps_coeff_kernel(
    const float* __restrict__ sp, float* __restrict__ coeff) {
  const int b = blockIdx.x;
  const int tid = threadIdx.x;
  if (tid < 38) {
    const int i = tid >> 1, d = tid & 1;
    const float* s = sp + b * 32 + d;
    float acc = 0.0f;
#pragma unroll
    for (int j = 0; j < 16; ++j) acc = fmaf(WM.w[i][j], s[2 * j], acc);
    coeff[b * CSTRIDE + tid] = acc;
  }
}

// ---------------------------------------------------------------------------
// Kernel 2: 8 px/thread, row-structured for write locality.
// Thread t owns 4 pixel-pairs at ix = 2t, rows bx*4 + j (j=0..3): every
// v4f store instruction is a fully-coalesced wave-contiguous 1 KiB run,
// and each block writes 16 KiB CONTIGUOUS per batch-step (was 4 KiB).
// XCD-bijective block swizzle groups 64 consecutive-px blocks per XCD ->
// ~1 MiB contiguous write run per XCD per batch-step.
// Coefficients are wave-uniform s_loads (SGPRs; no VGPR cost) so the
// 4x16 v2f RBF basis fits in registers without spilling.
// ---------------------------------------------------------------------------
__global__ __launch_bounds__(256) void tps_grid_kernel(
    const float* __restrict__ coeff, float* __restrict__ out) {
  const int lin = blockIdx.y * 128 + blockIdx.x;   // 0..511, nwg % 8 == 0
  const int swz = (lin & 7) * 64 + (lin >> 3);     // bijective XCD-contig remap
  const int bx = swz & 127, by = swz >> 7;
  const int tid = threadIdx.x;
  const int ix = 2 * tid;                          // 0..510, same all j
  const int b0 = by * BGRP;
  const float step = 2.0f / 511.0f;
  const v2f gxv = {-1.0f + ix * step, -1.0f + (ix + 1) * step};
  const float Xc[4] = {-1.0f, -1.0f / 3.0f, 1.0f / 3.0f, 1.0f};

  v2f dxp[4];
#pragma unroll
  for (int i = 0; i < 4; ++i) {
    v2f t = gxv - Xc[i];
    dxp[i] = t * t + 1e-6f;     // eps folded here (dy2 has none)
  }

  // basis for 4 pixel-pairs: rows iy = bx*4 + j, shared ix
  float gy4[4];
  v2f u[4][16];
#pragma unroll
  for (int j = 0; j < 4; ++j) {
    const float gy = -1.0f + (bx * 4 + j) * step;
    gy4[j] = gy;
    float dy2[4];
#pragma unroll
    for (int i = 0; i < 4; ++i) { float t = gy - Xc[i]; dy2[i] = t * t; }
#pragma unroll
    for (int k = 0; k < 16; ++k) {
      v2f t = dxp[k >> 2] + dy2[k & 3];                   // pk_add
      u[j][k] = t * (v2f){fast_log2(t.x), fast_log2(t.y)};
    }
  }

  // per-row store pointers (advance by one image per batch)
  float* op[4];
#pragma unroll
  for (int j = 0; j < 4; ++j)
    op[j] = out + ((size_t)b0 * HW + (size_t)(bx * 4 + j) * WW + ix) * 2;

  for (int bi = 0; bi < BGRP; ++bi) {
    const float* __restrict__ c = coeff + (b0 + bi) * CSTRIDE;  // wave-uniform
    float cc[38];
#pragma unroll
    for (int i = 0; i < 38; ++i) cc[i] = c[i];                  // -> s_load

    v2f ax[4], ay[4];
#pragma unroll
    for (int j = 0; j < 4; ++j) {
      ax[j] = cc[32] + gxv * cc[34] + gy4[j] * cc[36];
      ay[j] = cc[33] + gxv * cc[35] + gy4[j] * cc[37];
    }
#pragma unroll
    for (int k = 0; k < 16; ++k) {
#pragma unroll
      for (int j = 0; j < 4; ++j) {
        ax[j] += u[j][k] * cc[2 * k];                           // v_pk_fma
        ay[j] += u[j][k] * cc[2 * k + 1];
      }
    }

#pragma unroll
    for (int j = 0; j < 4; ++j) {
      v4f v = {ax[j].x, ay[j].x, ax[j].y, ay[j].y};
      *(v4f*)op[j] = v;            // wave-contiguous 1 KiB, full 128B lines
      op[j] += (size_t)HW * 2;
    }
  }
}

extern "C" void kernel_launch(void* const* d_in, const int* in_sizes, int n_in,
                              void* d_out, int out_size, void* d_ws, size_t ws_size,
                              hipStream_t stream) {
  const float* sp = (const float*)d_in[0];   // [B, K, 2] fp32
  float* out = (float*)d_out;                // [B, H, W, 2] fp32
  float* coeff = (float*)d_ws;               // BB * CSTRIDE floats

  tps_coeff_kernel<<<BB, 64, 0, stream>>>(sp, coeff);

  dim3 grid(128, BB / BGRP);                 // 128 row-quads x, 4 batch-groups y
  tps_grid_kernel<<<grid, 256, 0, stream>>>(coeff, out);
}